// Round 1
// baseline (351.558 us; speedup 1.0000x reference)
//
#include <hip/hip_runtime.h>
#include <hip/hip_bf16.h>

#define N_NODES  50000
#define N_EDGES  640000
#define IN_FEATS 512
#define HID      128
#define OUT_FEATS 128
#define N_GRAPHS 256

#define SCAN_CHUNK 1024
#define SCAN_BLOCKS ((N_NODES + SCAN_CHUNK - 1) / SCAN_CHUNK)   // 49

typedef __attribute__((ext_vector_type(8))) short short8;
typedef __attribute__((ext_vector_type(4))) float f32x4;

__device__ __forceinline__ float bf2f(unsigned u16) {
    return __uint_as_float(u16 << 16);
}
__device__ __forceinline__ unsigned short f2bf(float f) {
    __hip_bfloat16 h = __float2bfloat16(f);
    return *(unsigned short*)&h;
}

// ---------------- fused preprocessing: zero cnt | cvt W1 | cvt W2 | zero hs ----
// ranges: [0,196) zero cnt, [196,452) cvt1, [452,516) cvt2, [516,644) zero hs
#define PREP_BLOCKS 644

__global__ __launch_bounds__(256) void k_prep(const float* __restrict__ W1,
                                              const float* __restrict__ W2,
                                              unsigned short* __restrict__ wt1,
                                              unsigned short* __restrict__ wt2,
                                              int* __restrict__ cnt,
                                              float* __restrict__ hs) {
    int b = blockIdx.x;
    int t = threadIdx.x;
    if (b < 196) {
        int i = b * 256 + t;
        if (i < N_NODES) cnt[i] = 0;
    } else if (b < 452) {
        int idx = (b - 196) * 256 + t;
        int n = idx & 127, k = idx >> 7;
        wt1[(size_t)n * IN_FEATS + k] = f2bf(W1[(size_t)k * 128 + n]);
    } else if (b < 516) {
        int idx = (b - 452) * 256 + t;
        int n = idx & 127, k = idx >> 7;
        wt2[(size_t)n * HID + k] = f2bf(W2[(size_t)k * 128 + n]);
    } else {
        int idx = (b - 516) * 256 + t;
        hs[idx] = 0.f;
    }
}

// ------- FAT kernel: GEMM1 (wave-per-16-rows, LDS-free, barrier-free) + edge count -------
// gemm: Cb[M,128]bf16 = A[M,K]fp32 @ Bt[128][K]bf16^T
// Each wave owns rows [m0, m0+16) x all 128 cols. A-frag for mfma_16x16x32:
// lane l reads A[row=m0+(l&15)][k0 + (l>>4)*8 .. +8] -> two dwordx4, wave covers
// 16 rows x 128B fully coalesced. B-frag read direct from global (L2-hot).
// Register double-buffer: prefetch K-step k0+32 before MFMAs of k0. No LDS, no syncs.

template <int K>
__global__ __launch_bounds__(256, 3) void k_g1c(const float* __restrict__ A,
                                                const unsigned short* __restrict__ Bt,
                                                unsigned short* __restrict__ Cb, int M,
                                                const int* __restrict__ col,
                                                int* __restrict__ cnt, int nblk_gemm) {
    int tid = threadIdx.x;

    if (blockIdx.x >= nblk_gemm) {
        // -------- edge count part --------
        int e4 = ((blockIdx.x - nblk_gemm) * 256 + tid) * 4;
        if (e4 < N_EDGES) {
            int4 c = *(const int4*)(col + e4);
            atomicAdd(&cnt[c.x], 1);
            atomicAdd(&cnt[c.y], 1);
            atomicAdd(&cnt[c.z], 1);
            atomicAdd(&cnt[c.w], 1);
        }
        return;
    }

    // -------- gemm1 part --------
    int wave = tid >> 6;
    int lane = tid & 63;
    int quad = lane >> 4;
    int l15 = lane & 15;
    int m0 = blockIdx.x * 64 + wave * 16;

    int row = m0 + l15;
    if (row >= M) row = M - 1;
    const float* ap = A + (size_t)row * K + quad * 8;
    const unsigned short* bp = Bt + (size_t)l15 * K + quad * 8;

    f32x4 acc[8];
#pragma unroll
    for (int nt = 0; nt < 8; ++nt) acc[nt] = (f32x4){0.f, 0.f, 0.f, 0.f};

    // prime double buffer (k0 = 0)
    float4 a0 = *(const float4*)(ap);
    float4 a1 = *(const float4*)(ap + 4);
    short8 bcur[8];
#pragma unroll
    for (int nt = 0; nt < 8; ++nt)
        bcur[nt] = *(const short8*)(bp + (size_t)nt * 16 * K);

#pragma unroll 1
    for (int k0 = 0; k0 < K - 32; k0 += 32) {
        // prefetch next K-step
        float4 na0 = *(const float4*)(ap + k0 + 32);
        float4 na1 = *(const float4*)(ap + k0 + 36);
        short8 bn[8];
#pragma unroll
        for (int nt = 0; nt < 8; ++nt)
            bn[nt] = *(const short8*)(bp + (size_t)nt * 16 * K + k0 + 32);

        // convert current A to bf16 fragment
        short8 af;
        af[0] = (short)f2bf(a0.x); af[1] = (short)f2bf(a0.y);
        af[2] = (short)f2bf(a0.z); af[3] = (short)f2bf(a0.w);
        af[4] = (short)f2bf(a1.x); af[5] = (short)f2bf(a1.y);
        af[6] = (short)f2bf(a1.z); af[7] = (short)f2bf(a1.w);
#pragma unroll
        for (int nt = 0; nt < 8; ++nt)
            acc[nt] = __builtin_amdgcn_mfma_f32_16x16x32_bf16(af, bcur[nt], acc[nt], 0, 0, 0);

        a0 = na0; a1 = na1;
#pragma unroll
        for (int nt = 0; nt < 8; ++nt) bcur[nt] = bn[nt];
    }
    {   // tail K-step
        short8 af;
        af[0] = (short)f2bf(a0.x); af[1] = (short)f2bf(a0.y);
        af[2] = (short)f2bf(a0.z); af[3] = (short)f2bf(a0.w);
        af[4] = (short)f2bf(a1.x); af[5] = (short)f2bf(a1.y);
        af[6] = (short)f2bf(a1.z); af[7] = (short)f2bf(a1.w);
#pragma unroll
        for (int nt = 0; nt < 8; ++nt)
            acc[nt] = __builtin_amdgcn_mfma_f32_16x16x32_bf16(af, bcur[nt], acc[nt], 0, 0, 0);
    }

    // store: C row = m0 + quad*4 + r2, col = nt*16 + l15
#pragma unroll
    for (int nt = 0; nt < 8; ++nt) {
        int colb = nt * 16 + l15;
#pragma unroll
        for (int r2 = 0; r2 < 4; ++r2) {
            int gm = m0 + quad * 4 + r2;
            if (gm < M) Cb[(size_t)gm * 128 + colb] = f2bf(acc[nt][r2]);
        }
    }
}

// ---------------- scan ----------------

__global__ __launch_bounds__(256) void k_scan_a(const int* __restrict__ cnt,
                                                int* __restrict__ offs,
                                                int* __restrict__ bsum) {
    __shared__ int sums[256];
    int t = threadIdx.x;
    int base = blockIdx.x * SCAN_CHUNK + t * 4;
    int c0 = 0, c1 = 0, c2 = 0, c3 = 0;
    if (base + 3 < N_NODES) {
        int4 v = *(const int4*)(cnt + base);
        c0 = v.x; c1 = v.y; c2 = v.z; c3 = v.w;
    } else {
        if (base + 0 < N_NODES) c0 = cnt[base + 0];
        if (base + 1 < N_NODES) c1 = cnt[base + 1];
        if (base + 2 < N_NODES) c2 = cnt[base + 2];
    }
    int ts = c0 + c1 + c2 + c3;
    sums[t] = ts;
    __syncthreads();
#pragma unroll
    for (int off = 1; off < 256; off <<= 1) {
        int add = (t >= off) ? sums[t - off] : 0;
        __syncthreads();
        sums[t] += add;
        __syncthreads();
    }
    int ex = sums[t] - ts;
    if (base + 3 < N_NODES) {
        int4 o;
        o.x = ex; o.y = ex + c0; o.z = ex + c0 + c1; o.w = ex + c0 + c1 + c2;
        *(int4*)(offs + base) = o;
    } else {
        if (base + 0 < N_NODES) offs[base + 0] = ex;
        if (base + 1 < N_NODES) offs[base + 1] = ex + c0;
        if (base + 2 < N_NODES) offs[base + 2] = ex + c0 + c1;
    }
    if (t == 255) bsum[blockIdx.x] = sums[255];
}

__global__ __launch_bounds__(256) void k_scan_c(const int* __restrict__ cnt,
                                                const int* __restrict__ bsum,
                                                int* __restrict__ offs,
                                                int* __restrict__ cursor,
                                                float* __restrict__ dinv) {
    __shared__ int sb[64];
    int t = threadIdx.x;
    int b = blockIdx.x;
    if (t < 64) sb[t] = (t < SCAN_BLOCKS) ? bsum[t] : 0;
    __syncthreads();
#pragma unroll
    for (int off = 1; off < 64; off <<= 1) {
        int add = 0;
        if (t < 64 && t >= off) add = sb[t - off];
        __syncthreads();
        if (t < 64) sb[t] += add;
        __syncthreads();
    }
    int add = (b == 0) ? 0 : sb[b - 1];
    int base = b * SCAN_CHUNK + t * 4;
    if (base + 3 < N_NODES) {
        int4 o = *(const int4*)(offs + base);
        o.x += add; o.y += add; o.z += add; o.w += add;
        *(int4*)(offs + base) = o;
        *(int4*)(cursor + base) = o;
        int4 c = *(const int4*)(cnt + base);
        float4 d;
        d.x = rsqrtf((float)c.x + 1.0f);
        d.y = rsqrtf((float)c.y + 1.0f);
        d.z = rsqrtf((float)c.z + 1.0f);
        d.w = rsqrtf((float)c.w + 1.0f);
        *(float4*)(dinv + base) = d;
    } else {
#pragma unroll
        for (int j = 0; j < 4; ++j) {
            int i = base + j;
            if (i < N_NODES) {
                int o = offs[i] + add;
                offs[i] = o; cursor[i] = o;
                dinv[i] = rsqrtf((float)cnt[i] + 1.0f);
            }
        }
    }
    if (b == 0 && t == 0) offs[N_NODES] = N_EDGES;
}

__global__ void k_fill(const int* __restrict__ row, const int* __restrict__ col,
                       int* __restrict__ cursor, int* __restrict__ srcIdx) {
    int e4 = (blockIdx.x * blockDim.x + threadIdx.x) * 4;
    if (e4 >= N_EDGES) return;
    int4 r = *(const int4*)(row + e4);
    int4 c = *(const int4*)(col + e4);
    srcIdx[atomicAdd(&cursor[c.x], 1)] = r.x;
    srcIdx[atomicAdd(&cursor[c.y], 1)] = r.y;
    srcIdx[atomicAdd(&cursor[c.z], 1)] = r.z;
    srcIdx[atomicAdd(&cursor[c.w], 1)] = r.w;
}

// ---------------- aggregation: one WAVE per node, 2 edges/iter (half-wave parity) ----
// t rows are 64 uints (128 bf16). Lane l=lane&31 covers uints [2l,2l+1] = feats 4l..4l+3;
// half h=lane>>5 takes edge e+h. Predicated 16-edge chunks: invalid slots gather own row
// with weight 0 (cache-hot, exact). Cross-half combine via shfl_xor 32.

template <int RELU>
__global__ __launch_bounds__(256) void k_agg(const unsigned* __restrict__ t,
                                             const int* __restrict__ offs,
                                             const int* __restrict__ srcIdx,
                                             const float* __restrict__ dinv,
                                             const float* __restrict__ bias,
                                             unsigned* __restrict__ out_) {
    int wave = threadIdx.x >> 6;
    int lane = threadIdx.x & 63;
    int h = lane >> 5;
    int l = lane & 31;
    int i = blockIdx.x * 4 + wave;          // N_NODES % 4 == 0
    float di = dinv[i];
    const unsigned* my = t + (size_t)i * 64 + 2 * l;

    float s0 = 0.f, s1 = 0.f, s2 = 0.f, s3 = 0.f;
    {   // self term, half 0 only
        uint2 sv = *(const uint2*)my;
        if (h == 0) {
            s0 = bf2f(sv.x & 0xffffu) * di;
            s1 = bf2f(sv.x >> 16) * di;
            s2 = bf2f(sv.y & 0xffffu) * di;
            s3 = bf2f(sv.y >> 16) * di;
        }
    }
    int lo = offs[i], hi = offs[i + 1];
    for (int e = lo; e < hi; e += 16) {
        int idx[8];
        float d[8];
        uint2 v[8];
#pragma unroll
        for (int j = 0; j < 8; ++j) {
            int ee = e + 2 * j + h;
            idx[j] = (ee < hi) ? srcIdx[ee] : i;     // self row when invalid
        }
#pragma unroll
        for (int j = 0; j < 8; ++j)
            v[j] = *(const uint2*)(t + (size_t)idx[j] * 64 + 2 * l);
#pragma unroll
        for (int j = 0; j < 8; ++j) {
            int ee = e + 2 * j + h;
            d[j] = (ee < hi) ? dinv[idx[j]] : 0.f;   // weight 0 when invalid
        }
#pragma unroll
        for (int j = 0; j < 8; ++j) {
            s0 = fmaf(bf2f(v[j].x & 0xffffu), d[j], s0);
            s1 = fmaf(bf2f(v[j].x >> 16),     d[j], s1);
            s2 = fmaf(bf2f(v[j].y & 0xffffu), d[j], s2);
            s3 = fmaf(bf2f(v[j].y >> 16),     d[j], s3);
        }
    }
    // combine the two halves
    s0 += __shfl_xor(s0, 32);
    s1 += __shfl_xor(s1, 32);
    s2 += __shfl_xor(s2, 32);
    s3 += __shfl_xor(s3, 32);

    float r0 = s0 * di, r1 = s1 * di, r2 = s2 * di, r3 = s3 * di;
    if (bias) {
        float4 bb = *(const float4*)(bias + 4 * l);
        r0 += bb.x; r1 += bb.y; r2 += bb.z; r3 += bb.w;
    }
    if (RELU) {
        r0 = fmaxf(r0, 0.f); r1 = fmaxf(r1, 0.f);
        r2 = fmaxf(r2, 0.f); r3 = fmaxf(r3, 0.f);
    }
    if (h == 0) {
        uint2 o;
        o.x = (unsigned)f2bf(r0) | ((unsigned)f2bf(r1) << 16);
        o.y = (unsigned)f2bf(r2) | ((unsigned)f2bf(r3) << 16);
        *(uint2*)(out_ + (size_t)i * 64 + 2 * l) = o;
    }
}

// ------- GEMM2 + bias + fused pool: out[M,128]f32 = G[M,128]bf16 @ Bt^T + b;
//         hs[batch[m]] += out[m]  (rows batch-sorted -> grouped atomics) -------

__global__ __launch_bounds__(256) void k_gemm2_pool(const unsigned short* __restrict__ G,
                                                    const unsigned short* __restrict__ Bt,
                                                    const float* __restrict__ bias,
                                                    const int* __restrict__ batch,
                                                    float* __restrict__ out,
                                                    float* __restrict__ hs, int M) {
    const int K = HID;
    __shared__ unsigned short As[4][64][8];
    __shared__ unsigned short Bs[4][128][8];
    int tid = threadIdx.x;
    int wave = tid >> 6;
    int lane = tid & 63;
    int quad = lane >> 4;
    int l15 = lane & 15;
    int m0 = blockIdx.x * 64;

    f32x4 acc[8];
#pragma unroll
    for (int nt = 0; nt < 8; ++nt) acc[nt] = (f32x4){0.f, 0.f, 0.f, 0.f};

    int gm_a = m0 + lane; if (gm_a >= M) gm_a = M - 1;
    const unsigned short* ap_base = G + (size_t)gm_a * K + wave * 8;

    for (int k0 = 0; k0 < K; k0 += 32) {
        *(short8*)&As[wave][lane][0] = *(const short8*)(ap_base + k0);
#pragma unroll
        for (int i = 0; i < 2; ++i) {
            int slot = tid + i * 256;
            int bkq = slot >> 7;
            int n = slot & 127;
            *(short8*)&Bs[bkq][n][0] = *(const short8*)(Bt + (size_t)n * K + k0 + bkq * 8);
        }
        __syncthreads();
        short8 a = *(short8*)&As[quad][wave * 16 + l15][0];
#pragma unroll
        for (int nt = 0; nt < 8; ++nt) {
            short8 b = *(short8*)&Bs[quad][nt * 16 + l15][0];
            acc[nt] = __builtin_amdgcn_mfma_f32_16x16x32_bf16(a, b, acc[nt], 0, 0, 0);
        }
        __syncthreads();
    }
    int rb = m0 + wave * 16 + quad * 4;
    int g_[4];
#pragma unroll
    for (int r2 = 0; r2 < 4; ++r2)
        g_[r2] = (rb + r2 < M) ? batch[rb + r2] : -1;
#pragma unroll
    for (int nt = 0; nt < 8; ++nt) {
        int colb = nt * 16 + l15;
        float bcol = bias[colb];
        float v[4];
#pragma unroll
        for (int r2 = 0; r2 < 4; ++r2) {
            v[r2] = acc[nt][r2] + bcol;
            if (rb + r2 < M) out[(size_t)(rb + r2) * 128 + colb] = v[r2];
        }
        float run = v[0];
        int gcur = g_[0];
#pragma unroll
        for (int r2 = 1; r2 < 4; ++r2) {
            if (g_[r2] == gcur) run += v[r2];
            else {
                if (gcur >= 0) atomicAdd(&hs[(size_t)gcur * 128 + colb], run);
                gcur = g_[r2]; run = v[r2];
            }
        }
        if (gcur >= 0) atomicAdd(&hs[(size_t)gcur * 128 + colb], run);
    }
}

// ---------------- launch ----------------

extern "C" void kernel_launch(void* const* d_in, const int* in_sizes, int n_in,
                              void* d_out, int out_size, void* d_ws, size_t ws_size,
                              hipStream_t stream) {
    const float* x  = (const float*)d_in[0];
    const float* W1 = (const float*)d_in[1];
    const float* b1 = (const float*)d_in[2];
    const float* W2 = (const float*)d_in[3];
    const float* b2 = (const float*)d_in[4];
    const int*   ei = (const int*)d_in[5];
    const int*   batch = (const int*)d_in[6];
    const int* row = ei;
    const int* col = ei + N_EDGES;

    float* out_hs = (float*)d_out;
    float* out_h  = (float*)d_out + N_GRAPHS * OUT_FEATS;

    char* ws = (char*)d_ws;
    unsigned short* tb   = (unsigned short*)ws;                  // 12,800,000
    unsigned short* h1b  = (unsigned short*)(ws + 12800000);     // 12,800,000
    unsigned short* gb   = (unsigned short*)(ws + 25600000);     // 12,800,000
    float* dinv = (float*)(ws + 38400000);
    int*   cnt    = (int*)(ws + 38600000);
    int*   offs   = (int*)(ws + 38800000);
    int*   cursor = (int*)(ws + 39000016);
    int*   srcIdx = (int*)(ws + 39200016);
    int*   bsum   = (int*)(ws + 41761056);
    unsigned short* wt1 = (unsigned short*)(ws + 41761472);
    unsigned short* wt2 = (unsigned short*)(ws + 41892544);

    const int TB = 256;
    const int GB1 = (N_NODES + 63) / 64;                 // 782 gemm blocks (64 rows/block, 16/wave)
    const int CB  = (N_EDGES / 4 + TB - 1) / TB;         // 625 count blocks

    k_prep<<<PREP_BLOCKS, 256, 0, stream>>>(W1, W2, wt1, wt2, cnt, out_hs);
    // gemm1 + edge-count fat kernel (independent work, concurrent)
    k_g1c<IN_FEATS><<<GB1 + CB, 256, 0, stream>>>(x, wt1, tb, N_NODES, col, cnt, GB1);
    k_scan_a<<<SCAN_BLOCKS, 256, 0, stream>>>(cnt, offs, bsum);
    k_scan_c<<<SCAN_BLOCKS, 256, 0, stream>>>(cnt, bsum, offs, cursor, dinv);
    k_fill<<<(N_EDGES / 4 + TB - 1) / TB, TB, 0, stream>>>(row, col, cursor, srcIdx);

    // layer 1 agg (+b1, ReLU) -> bf16 h1
    k_agg<1><<<N_NODES / 4, 256, 0, stream>>>((const unsigned*)tb, offs, srcIdx, dinv, b1, (unsigned*)h1b);
    // layer 2 (commuted): agg h1 (no bias) -> g, then GEMM2 (+b2) with fused pool
    k_agg<0><<<N_NODES / 4, 256, 0, stream>>>((const unsigned*)h1b, offs, srcIdx, dinv, nullptr, (unsigned*)gb);
    k_gemm2_pool<<<(N_NODES + 63) / 64, 256, 0, stream>>>(gb, wt2, b2, batch, out_h, out_hs, N_NODES);
}